// Round 14
// baseline (275.434 us; speedup 1.0000x reference)
//
#include <hip/hip_runtime.h>

typedef unsigned short u16;
typedef short bf16x8 __attribute__((ext_vector_type(8)));
typedef float f32x4 __attribute__((ext_vector_type(4)));

__device__ __forceinline__ u16 f2bf(float f) {
    unsigned u = __float_as_uint(f);
    return (u16)((u + 0x7fffu + ((u >> 16) & 1u)) >> 16);
}
__device__ __forceinline__ float exp2_hw(float x) {
    float r;
    asm("v_exp_f32 %0, %1" : "=v"(r) : "v"(x));
    return r;
}
template <int CTRL>
__device__ __forceinline__ float dpp_add(float p) {
    int t = __builtin_amdgcn_update_dpp(0, __float_as_int(p), CTRL, 0xf, 0xf, true);
    return p + __int_as_float(t);
}
__device__ __forceinline__ void gload_lds16(const u16* g, u16* lds) {
    __builtin_amdgcn_global_load_lds((const __attribute__((address_space(1))) void*)g,
                                     (__attribute__((address_space(3))) void*)lds, 16, 0, 0);
}

struct MegaP {
    const float* x; const int* ei;
    const float *W1l, *b1l, *W1r, *b1r, *att1, *bias1;
    const float *W2l, *b2l, *W2r, *b2r, *att2, *bias2;
    const float *Wp1, *bp1, *Wp2, *bp2;
    u16 *Abuf, *XLR, *BF1, *BF2, *BFp;
    float *bc1, *bc2, *bpf;
    int *cnt; u16 *slot;
    float* outF;
    int N, E, Mpad, Mt;
};

// ---------------- GEMM v2 (device fn): A full-K LDS-resident, B from L2 in fragment order ----
// C[M,Nout] = A[M,256] @ B^T + bias. A: 128 rows x 256 K staged ONCE into LDS (XOR chunk
// swizzle, one barrier). B pre-packed in fragment order: Bf[(g*32+kc)*128 + lrow*8 + j]
// where g = col>>4, kc = k>>3 -> per-wave fragment load = 4 contiguous 256B segments (L2-hot,
// B is only 256KB). Block loops CT col-panels of 64*NRF cols; 8 waves (2x4),
// wave tile 64 x (NRF*16). LDS = 64KB -> 2 blocks/CU.

template <bool AF32, int NRF, int CT, bool F32OUT>
__device__ __forceinline__ void gemm_v2(const void* __restrict__ Av, const u16* __restrict__ Bf,
                                        const float* __restrict__ bias, void* __restrict__ out,
                                        int M, int Nout, int bm, u16* As) {
    constexpr int K = 256;
    constexpr int PANEL = NRF * 64;
    const int tid = threadIdx.x;
    const int l = tid & 63;
    const int w = tid >> 6;
    const int wm = w >> 2, wn = w & 3;
    const int lrow = l & 15, lk = l >> 4;
    const int wbase = tid & ~63;

    // ---- stage A full-K once (4096 chunks of 16B; LDS chunk c holds global chunk (c&31)^(row&7)) ----
    if (AF32) {
        const float* A32 = (const float*)Av;
#pragma unroll
        for (int it = 0; it < 8; ++it) {
            int c = it * 512 + tid;
            int row = c >> 5, ch = c & 31;
            int grow = bm * 128 + row;
            if (grow > M - 1) grow = M - 1;
            int ssrc = ch ^ (row & 7);
            const float* sp = A32 + (size_t)grow * K + ssrc * 8;
            float4 v0 = *(const float4*)sp;
            float4 v1 = *(const float4*)(sp + 4);
            bf16x8 pk;
            pk[0] = (short)f2bf(v0.x); pk[1] = (short)f2bf(v0.y);
            pk[2] = (short)f2bf(v0.z); pk[3] = (short)f2bf(v0.w);
            pk[4] = (short)f2bf(v1.x); pk[5] = (short)f2bf(v1.y);
            pk[6] = (short)f2bf(v1.z); pk[7] = (short)f2bf(v1.w);
            *(bf16x8*)(As + (size_t)c * 8) = pk;
        }
    } else {
        const u16* Abf = (const u16*)Av;
#pragma unroll
        for (int it = 0; it < 8; ++it) {
            int c = it * 512 + tid;
            int row = c >> 5, ch = c & 31;
            int ssrc = ch ^ (row & 7);
            gload_lds16(Abf + (size_t)(bm * 128 + row) * K + ssrc * 8,
                        As + (size_t)(it * 512 + wbase) * 8);
        }
    }
    __syncthreads();  // the ONLY barrier

    for (int bn = 0; bn < CT; ++bn) {
        f32x4 acc[4][NRF];
#pragma unroll
        for (int m = 0; m < 4; ++m)
#pragma unroll
            for (int n = 0; n < NRF; ++n) acc[m][n] = (f32x4){0.f, 0.f, 0.f, 0.f};

#pragma unroll
        for (int ks = 0; ks < 8; ++ks) {
            const int kc = ks * 4 + lk;
            bf16x8 av[4], bv[NRF];
#pragma unroll
            for (int m = 0; m < 4; ++m) {
                int row = wm * 64 + m * 16 + lrow;
                av[m] = *(const bf16x8*)(As + row * K + ((kc ^ (row & 7)) * 8));
            }
#pragma unroll
            for (int n = 0; n < NRF; ++n) {
                int g = bn * (4 * NRF) + wn * NRF + n;
                bv[n] = *(const bf16x8*)(Bf + ((size_t)g * 32 + kc) * 128 + lrow * 8);
            }
#pragma unroll
            for (int m = 0; m < 4; ++m)
#pragma unroll
                for (int n = 0; n < NRF; ++n)
                    acc[m][n] = __builtin_amdgcn_mfma_f32_16x16x32_bf16(av[m], bv[n], acc[m][n], 0, 0, 0);
        }

        float bl[NRF];
#pragma unroll
        for (int n = 0; n < NRF; ++n) bl[n] = bias[bn * PANEL + wn * (NRF * 16) + n * 16 + lrow];

#pragma unroll
        for (int m = 0; m < 4; ++m) {
            int grow = bm * 128 + wm * 64 + m * 16 + lk * 4;
#pragma unroll
            for (int j = 0; j < 4; ++j) {
                if (grow + j < M) {
#pragma unroll
                    for (int n = 0; n < NRF; ++n) {
                        int col = bn * PANEL + wn * (NRF * 16) + n * 16 + lrow;
                        float v = acc[m][n][j] + bl[n];
                        if (F32OUT)
                            ((float*)out)[(size_t)(grow + j) * Nout + col] = v;
                        else
                            ((u16*)out)[(size_t)(grow + j) * Nout + col] = f2bf(v);
                    }
                }
            }
        }
    }
}

// ---------------- prep kernel: fragment-order weights + bias + postW + XCD-sharded scatter ----

__global__ __launch_bounds__(256) void k_prep(MegaP P) {
    const int N = P.N, E = P.E;
    const int c0 = 1024, c1 = c0 + 64, c2 = c1 + 4;
    int b = blockIdx.x;
    int tid = threadIdx.x;
    if (b < c0) {  // weight -> fragment order: Bf[((col>>4)*32 + (k>>3))*128 + (col&15)*8 + (k&7)]
        int n = b & 255, m = b >> 8;
        const float* W = (m == 0) ? P.W1l : (m == 1) ? P.W1r : (m == 2) ? P.W2l : P.W2r;
        u16* dst = (m < 2) ? P.BF1 : P.BF2;
        int col = (m & 1) * 256 + n;
        int k = tid;
        dst[((size_t)(col >> 4) * 32 + (k >> 3)) * 128 + (col & 15) * 8 + (k & 7)] =
            f2bf(W[(size_t)k * 256 + n]);
    } else if (b < c1) {  // fused post-MLP weight, fragment order
        int j = b - c0;  // col 0..63
        float a = 0.f;
        for (int k = 0; k < 64; ++k) a += P.Wp1[tid * 64 + k] * P.Wp2[k * 64 + j];
        P.BFp[((size_t)(j >> 4) * 32 + (tid >> 3)) * 128 + (j & 15) * 8 + (tid & 7)] = f2bf(a);
        if (tid == 0) {
            float bb = P.bp2[j];
            for (int k = 0; k < 64; ++k) bb += P.bp1[k] * P.Wp2[k * 64 + j];
            P.bpf[j] = bb;
        }
    } else if (b < c2) {  // bias concat
        int m = b - c1;
        const float* s = (m == 0) ? P.b1l : (m == 1) ? P.b1r : (m == 2) ? P.b2l : P.b2r;
        float* d = (m < 2) ? P.bc1 : P.bc2;
        d[(m & 1) * 256 + tid] = s[tid];
    } else {  // XCD-sharded scatter (self-loops NOT stored; edge kernel adds them inline)
        int bi = b - c2;
        int xcd = bi & 7;
        int e = (bi >> 3) * 256 + tid;
        if (e < E) {
            int dst = P.ei[E + e];
            int S = (N + 7) >> 3;
            if ((unsigned)(dst - xcd * S) < (unsigned)S) {
                int src = P.ei[e];
                int p = atomicAdd(P.cnt + dst, 1);
                if (p < 64) P.slot[((size_t)dst << 6) + p] = (u16)src;
            }
        }
    }
}

// ---------------- GEMM kernels ----------------

__global__ __launch_bounds__(512) void k_g1(MegaP P) {
    __shared__ __align__(16) u16 As[32768];
    gemm_v2<true, 2, 4, false>(P.x, P.BF1, P.bc1, P.XLR, P.N, 512, blockIdx.x, As);
}
__global__ __launch_bounds__(512) void k_g2(MegaP P) {
    __shared__ __align__(16) u16 As[32768];
    gemm_v2<false, 2, 4, false>(P.Abuf, P.BF2, P.bc2, P.XLR, P.N, 512, blockIdx.x, As);
}
__global__ __launch_bounds__(512) void k_gp(MegaP P) {
    __shared__ __align__(16) u16 As[32768];
    gemm_v2<false, 1, 1, true>(P.Abuf, P.BFp, P.bpf, P.outF, P.N, 64, blockIdx.x, As);
}

// ---------------- GATv2 edge kernel: one wave per dst node; self-loop inline ----------------

__global__ __launch_bounds__(256) void k_edge(const int* __restrict__ cnt,
                                              const u16* __restrict__ slot,
                                              const u16* __restrict__ XLR,
                                              const float* __restrict__ att,
                                              const float* __restrict__ bias,
                                              u16* __restrict__ H, int N) {
    int wid0 = blockIdx.x * 4 + (threadIdx.x >> 6);
    if (wid0 >= N) return;
    const int wid = __builtin_amdgcn_readfirstlane(wid0);
    const int l = threadIdx.x & 63;

    const float LOG2E = 1.4426950408889634f;
    float4 a4 = *(const float4*)(att + l * 4);
    a4.x *= LOG2E; a4.y *= LOG2E; a4.z *= LOG2E; a4.w *= LOG2E;
    float4 bb = *(const float4*)(bias + l * 4);
    const char* Xb = (const char*)XLR;
    const int lofs = l << 3;

    uint2 xr = *(const uint2*)(Xb + ((size_t)wid << 10) + 512 + lofs);
    float r0 = __uint_as_float(xr.x << 16), r1 = __uint_as_float(xr.x & 0xffff0000u);
    float r2 = __uint_as_float(xr.y << 16), r3 = __uint_as_float(xr.y & 0xffff0000u);

    const u16* sl = slot + ((size_t)wid << 6);
    int deg = cnt[wid];
    if (deg > 64) deg = 64;
    float s = 0.f, o0 = 0.f, o1 = 0.f, o2 = 0.f, o3 = 0.f;

    auto edge1 = [&](uint2 wv) {
        float c0 = __uint_as_float(wv.x << 16), c1 = __uint_as_float(wv.x & 0xffff0000u);
        float c2 = __uint_as_float(wv.y << 16), c3 = __uint_as_float(wv.y & 0xffff0000u);
        float t0 = c0 + r0, t1 = c1 + r1, t2 = c2 + r2, t3 = c3 + r3;
        t0 = fmaf(-0.8f, fminf(t0, 0.f), t0);
        t1 = fmaf(-0.8f, fminf(t1, 0.f), t1);
        t2 = fmaf(-0.8f, fminf(t2, 0.f), t2);
        t3 = fmaf(-0.8f, fminf(t3, 0.f), t3);
        float p = t0 * a4.x; p = fmaf(t1, a4.y, p); p = fmaf(t2, a4.z, p); p = fmaf(t3, a4.w, p);
        p = dpp_add<0xB1>(p);   // xor1
        p = dpp_add<0x4E>(p);   // xor2
        p = dpp_add<0x141>(p);  // row_half_mirror
        p = dpp_add<0x140>(p);  // row_mirror
        float e = exp2_hw(p);
        s += e;
        o0 = fmaf(e, c0, o0); o1 = fmaf(e, c1, o1);
        o2 = fmaf(e, c2, o2); o3 = fmaf(e, c3, o3);
    };

    // self-loop (u = wid), never stored in slot
    {
        uint2 w0 = *(const uint2*)(Xb + ((size_t)wid << 10) + lofs);
        edge1(w0);
    }

    int i = 0;
    for (; i + 8 <= deg; i += 8) {
        int u0 = __builtin_amdgcn_readfirstlane(sl[i]);
        int u1 = __builtin_amdgcn_readfirstlane(sl[i + 1]);
        int u2 = __builtin_amdgcn_readfirstlane(sl[i + 2]);
        int u3 = __builtin_amdgcn_readfirstlane(sl[i + 3]);
        int u4 = __builtin_amdgcn_readfirstlane(sl[i + 4]);
        int u5 = __builtin_amdgcn_readfirstlane(sl[i + 5]);
        int u6 = __builtin_amdgcn_readfirstlane(sl[i + 6]);
        int u7 = __builtin_amdgcn_readfirstlane(sl[i + 7]);
        uint2 w0 = *(const uint2*)(Xb + ((size_t)u0 << 10) + lofs);
        uint2 w1 = *(const uint2*)(Xb + ((size_t)u1 << 10) + lofs);
        uint2 w2 = *(const uint2*)(Xb + ((size_t)u2 << 10) + lofs);
        uint2 w3 = *(const uint2*)(Xb + ((size_t)u3 << 10) + lofs);
        uint2 w4 = *(const uint2*)(Xb + ((size_t)u4 << 10) + lofs);
        uint2 w5 = *(const uint2*)(Xb + ((size_t)u5 << 10) + lofs);
        uint2 w6 = *(const uint2*)(Xb + ((size_t)u6 << 10) + lofs);
        uint2 w7 = *(const uint2*)(Xb + ((size_t)u7 << 10) + lofs);
        edge1(w0); edge1(w1); edge1(w2); edge1(w3);
        edge1(w4); edge1(w5); edge1(w6); edge1(w7);
    }
    for (; i + 4 <= deg; i += 4) {
        int u0 = __builtin_amdgcn_readfirstlane(sl[i]);
        int u1 = __builtin_amdgcn_readfirstlane(sl[i + 1]);
        int u2 = __builtin_amdgcn_readfirstlane(sl[i + 2]);
        int u3 = __builtin_amdgcn_readfirstlane(sl[i + 3]);
        uint2 w0 = *(const uint2*)(Xb + ((size_t)u0 << 10) + lofs);
        uint2 w1 = *(const uint2*)(Xb + ((size_t)u1 << 10) + lofs);
        uint2 w2 = *(const uint2*)(Xb + ((size_t)u2 << 10) + lofs);
        uint2 w3 = *(const uint2*)(Xb + ((size_t)u3 << 10) + lofs);
        edge1(w0); edge1(w1); edge1(w2); edge1(w3);
    }
    for (; i < deg; ++i) {
        int u0 = __builtin_amdgcn_readfirstlane(sl[i]);
        uint2 w0 = *(const uint2*)(Xb + ((size_t)u0 << 10) + lofs);
        edge1(w0);
    }

    float inv = 1.f / s;
    o0 = fmaxf(fmaf(o0, inv, bb.x), 0.f);
    o1 = fmaxf(fmaf(o1, inv, bb.y), 0.f);
    o2 = fmaxf(fmaf(o2, inv, bb.z), 0.f);
    o3 = fmaxf(fmaf(o3, inv, bb.w), 0.f);
    ushort4 w4 = {f2bf(o0), f2bf(o1), f2bf(o2), f2bf(o3)};
    *(ushort4*)(H + ((size_t)wid << 8) + l * 4) = w4;
}

// ---------------- launcher ----------------

extern "C" void kernel_launch(void* const* d_in, const int* in_sizes, int n_in,
                              void* d_out, int out_size, void* d_ws, size_t ws_size,
                              hipStream_t stream) {
    MegaP P;
    P.x     = (const float*)d_in[0];
    P.ei    = (const int*)d_in[1];
    P.W1l   = (const float*)d_in[2];  P.b1l  = (const float*)d_in[3];
    P.W1r   = (const float*)d_in[4];  P.b1r  = (const float*)d_in[5];
    P.att1  = (const float*)d_in[6];  P.bias1 = (const float*)d_in[7];
    P.W2l   = (const float*)d_in[8];  P.b2l  = (const float*)d_in[9];
    P.W2r   = (const float*)d_in[10]; P.b2r  = (const float*)d_in[11];
    P.att2  = (const float*)d_in[12]; P.bias2 = (const float*)d_in[13];
    P.Wp1   = (const float*)d_in[14]; P.bp1  = (const float*)d_in[15];
    P.Wp2   = (const float*)d_in[16]; P.bp2  = (const float*)d_in[17];

    const int N = in_sizes[0] / 256;
    const int E = in_sizes[1] / 2;
    const int Mpad = ((N + 127) / 128) * 128;

    char* ws = (char*)d_ws;
    size_t o = 0;
    auto alloc = [&](size_t b) { char* p = ws + o; o = (o + b + 255) & ~(size_t)255; return p; };
    P.Abuf   = (u16*)alloc((size_t)Mpad * 256 * 2);
    P.XLR    = (u16*)alloc((size_t)Mpad * 512 * 2);
    P.BF1    = (u16*)alloc(512 * 256 * 2);
    P.BF2    = (u16*)alloc(512 * 256 * 2);
    P.BFp    = (u16*)alloc(64 * 256 * 2);
    P.bc1    = (float*)alloc(512 * 4);
    P.bc2    = (float*)alloc(512 * 4);
    P.bpf    = (float*)alloc(64 * 4);
    P.cnt    = (int*)alloc((size_t)N * 4);
    P.slot   = (u16*)alloc((size_t)N * 64 * 2);
    P.outF   = (float*)d_out;
    P.N = N; P.E = E; P.Mpad = Mpad; P.Mt = Mpad / 128;

    hipMemsetAsync(P.cnt, 0, (size_t)N * 4, stream);
    if (Mpad > N)
        hipMemsetAsync(P.Abuf + (size_t)N * 256, 0, (size_t)(Mpad - N) * 256 * 2, stream);

    // prep: fragment-order weights + bias + postW + XCD-sharded scatter
    const int nScat = ((E + 255) / 256) * 8;
    k_prep<<<1024 + 64 + 4 + nScat, 256, 0, stream>>>(P);

    const int egrid = (N + 3) / 4;
    k_g1<<<P.Mt, 512, 0, stream>>>(P);
    k_edge<<<egrid, 256, 0, stream>>>(P.cnt, P.slot, P.XLR, P.att1, P.bias1, P.Abuf, N);
    k_g2<<<P.Mt, 512, 0, stream>>>(P);
    k_edge<<<egrid, 256, 0, stream>>>(P.cnt, P.slot, P.XLR, P.att2, P.bias2, P.Abuf, N);
    k_gp<<<P.Mt, 512, 0, stream>>>(P);
}

// Round 15
// 256.793 us; speedup vs baseline: 1.0726x; 1.0726x over previous
//
#include <hip/hip_runtime.h>

typedef unsigned short u16;
typedef short bf16x8 __attribute__((ext_vector_type(8)));
typedef float f32x4 __attribute__((ext_vector_type(4)));

__device__ __forceinline__ u16 f2bf(float f) {
    unsigned u = __float_as_uint(f);
    return (u16)((u + 0x7fffu + ((u >> 16) & 1u)) >> 16);
}
__device__ __forceinline__ float exp2_hw(float x) {
    float r;
    asm("v_exp_f32 %0, %1" : "=v"(r) : "v"(x));
    return r;
}
template <int CTRL>
__device__ __forceinline__ float dpp_add(float p) {
    int t = __builtin_amdgcn_update_dpp(0, __float_as_int(p), CTRL, 0xf, 0xf, true);
    return p + __int_as_float(t);
}
__device__ __forceinline__ void gload_lds16(const u16* g, u16* lds) {
    __builtin_amdgcn_global_load_lds((const __attribute__((address_space(1))) void*)g,
                                     (__attribute__((address_space(3))) void*)lds, 16, 0, 0);
}

struct MegaP {
    const float* x; const int* ei;
    const float *W1l, *b1l, *W1r, *b1r, *att1, *bias1;
    const float *W2l, *b2l, *W2r, *b2r, *att2, *bias2;
    const float *Wp1, *bp1, *Wp2, *bp2;
    u16 *Xbf, *Abuf, *XLR, *WB1, *WB2, *Wpt;
    float *bc1, *bc2, *bpf;
    int *cnt; u16 *slot;
    float* outF;
    int N, E, Mpad, Mt;
};

// ---------------- GEMM tile (r13 structure): one 128 x BN tile of C = A[M,256] @ Bt^T + bias ----
// B panel (BN x 256) LDS-resident (XOR chunk swizzle); A staged per BK=64 via global_load_lds.
// 8 waves (2x4), wave tile 64 x (NRF*16).

template <int BN, bool F32OUT>
__device__ __forceinline__ void gemm_tile(const u16* __restrict__ Abf, const u16* __restrict__ Bt,
                                          const float* __restrict__ bias, void* __restrict__ out,
                                          int M, int Nout, int bm, int bn, u16* As, u16* Bs) {
    constexpr int K = 256;
    constexpr int NRF = BN / 64;
    const int tid = threadIdx.x;
    const int l = tid & 63;
    const int w = tid >> 6;
    const int wm = w >> 2, wn = w & 3;
    const int lrow = l & 15, lk = l >> 4;
    const int wbase = tid & ~63;

#pragma unroll
    for (int it = 0; it < BN / 16; ++it) {  // stage B panel (XOR chunk swizzle)
        int c = it * 512 + tid;
        int col = c >> 5, kc = c & 31;
        bf16x8 v = *(const bf16x8*)(Bt + (size_t)(bn * BN + col) * K + kc * 8);
        *(bf16x8*)(Bs + col * K + ((kc ^ (col & 7)) * 8)) = v;
    }

    auto stageA = [&](int ks) {
#pragma unroll
        for (int it = 0; it < 2; ++it) {
            int c = it * 512 + tid;
            int row = c >> 3, seg = c & 7;
            int ssrc = seg ^ (row & 7);
            gload_lds16(Abf + (size_t)(bm * 128 + row) * K + ks * 64 + ssrc * 8,
                        As + (size_t)(it * 512 + wbase) * 8);
        }
    };

    f32x4 acc[4][NRF];
#pragma unroll
    for (int m = 0; m < 4; ++m)
#pragma unroll
        for (int n = 0; n < NRF; ++n) acc[m][n] = (f32x4){0.f, 0.f, 0.f, 0.f};

    stageA(0);
    __syncthreads();

    for (int ks = 0; ks < 4; ++ks) {
#pragma unroll
        for (int h = 0; h < 2; ++h) {
            bf16x8 av[4], bv[NRF];
#pragma unroll
            for (int m = 0; m < 4; ++m) {
                int row = wm * 64 + m * 16 + lrow;
                int seg = ((h * 4 + lk) ^ (row & 7));
                av[m] = *(const bf16x8*)(As + row * 64 + seg * 8);
            }
#pragma unroll
            for (int n = 0; n < NRF; ++n) {
                int col = wn * (NRF * 16) + n * 16 + lrow;
                int kc = ks * 8 + h * 4 + lk;
                bv[n] = *(const bf16x8*)(Bs + col * K + ((kc ^ (col & 7)) * 8));
            }
#pragma unroll
            for (int m = 0; m < 4; ++m)
#pragma unroll
                for (int n = 0; n < NRF; ++n)
                    acc[m][n] = __builtin_amdgcn_mfma_f32_16x16x32_bf16(av[m], bv[n], acc[m][n], 0, 0, 0);
        }
        if (ks < 3) {
            __syncthreads();
            stageA(ks + 1);
            __syncthreads();
        }
    }

    float bl[NRF];
#pragma unroll
    for (int n = 0; n < NRF; ++n) bl[n] = bias[bn * BN + wn * (NRF * 16) + n * 16 + lrow];

#pragma unroll
    for (int m = 0; m < 4; ++m) {
        int grow = bm * 128 + wm * 64 + m * 16 + lk * 4;
#pragma unroll
        for (int j = 0; j < 4; ++j) {
            if (grow + j < M) {
#pragma unroll
                for (int n = 0; n < NRF; ++n) {
                    int col = bn * BN + wn * (NRF * 16) + n * 16 + lrow;
                    float v = acc[m][n][j] + bl[n];
                    if (F32OUT)
                        ((float*)out)[(size_t)(grow + j) * Nout + col] = v;
                    else
                        ((u16*)out)[(size_t)(grow + j) * Nout + col] = f2bf(v);
                }
            }
        }
    }
}

// XCD-aware tile map for ct=4 col-tiles: all 4 col-tiles of one bm get the same d%8.
__device__ __forceinline__ void tile_map4(int d, int Mt, int& bm, int& bn) {
    int nfull = (Mt & ~7) * 4;
    if (d < nfull) {
        int g = d >> 5, r = d & 31;
        bm = g * 8 + (r & 7);
        bn = r >> 3;
    } else {
        int idx = d - nfull;
        bm = (Mt & ~7) + (idx >> 2);
        bn = idx & 3;
    }
}

// ---------------- prep kernel: weights + bias + postW + x->bf16 cvt + XCD-sharded scatter ----

__global__ __launch_bounds__(256) void k_prep(MegaP P) {
    const int N = P.N, E = P.E;
    const int nCvt = (N * 64 + 255) / 256;  // N*256/4 threads, 4 floats each
    const int c0 = 1024, c1 = c0 + 64, c2 = c1 + 4, c3 = c2 + nCvt;
    int b = blockIdx.x;
    int tid = threadIdx.x;
    if (b < c0) {  // weight transpose: WB = [Wl^T ; Wr^T] bf16
        int n = b & 255, m = b >> 8;
        const float* W = (m == 0) ? P.W1l : (m == 1) ? P.W1r : (m == 2) ? P.W2l : P.W2r;
        u16* dst = (m < 2) ? P.WB1 : P.WB2;
        dst[(size_t)((m & 1) * 256 + n) * 256 + tid] = f2bf(W[(size_t)tid * 256 + n]);
    } else if (b < c1) {  // fused post-MLP weight
        int j = b - c0;
        float a = 0.f;
        for (int k = 0; k < 64; ++k) a += P.Wp1[tid * 64 + k] * P.Wp2[k * 64 + j];
        P.Wpt[j * 256 + tid] = f2bf(a);
        if (tid == 0) {
            float bb = P.bp2[j];
            for (int k = 0; k < 64; ++k) bb += P.bp1[k] * P.Wp2[k * 64 + j];
            P.bpf[j] = bb;
        }
    } else if (b < c2) {  // bias concat
        int m = b - c1;
        const float* s = (m == 0) ? P.b1l : (m == 1) ? P.b1r : (m == 2) ? P.b2l : P.b2r;
        float* d = (m < 2) ? P.bc1 : P.bc2;
        d[(m & 1) * 256 + tid] = s[tid];
    } else if (b < c3) {  // x -> bf16
        long i = ((long)(b - c2) * 256 + tid) * 4;
        if (i + 3 < (long)N * 256) {
            float4 v = *(const float4*)(P.x + i);
            ushort4 w4 = {f2bf(v.x), f2bf(v.y), f2bf(v.z), f2bf(v.w)};
            *(ushort4*)(P.Xbf + i) = w4;
        }
    } else {  // XCD-sharded scatter (self-loops NOT stored; edge kernel adds them inline)
        int bi = b - c3;
        int xcd = bi & 7;
        int e = (bi >> 3) * 256 + tid;
        if (e < E) {
            int dst = P.ei[E + e];
            int S = (N + 7) >> 3;
            if ((unsigned)(dst - xcd * S) < (unsigned)S) {
                int src = P.ei[e];
                int p = atomicAdd(P.cnt + dst, 1);
                if (p < 64) P.slot[((size_t)dst << 6) + p] = (u16)src;
            }
        }
    }
}

// ---------------- GEMM kernels ----------------

__global__ __launch_bounds__(512) void k_g1(MegaP P) {
    __shared__ __align__(16) u16 As[8192];
    __shared__ __align__(16) u16 Bs[32768];
    int bm, bn;
    tile_map4(blockIdx.x, P.Mt, bm, bn);
    gemm_tile<128, false>(P.Xbf, P.WB1, P.bc1, P.XLR, P.N, 512, bm, bn, As, Bs);
}

__global__ __launch_bounds__(512) void k_g2(MegaP P) {
    __shared__ __align__(16) u16 As[8192];
    __shared__ __align__(16) u16 Bs[32768];
    int bm, bn;
    tile_map4(blockIdx.x, P.Mt, bm, bn);
    gemm_tile<128, false>(P.Abuf, P.WB2, P.bc2, P.XLR, P.N, 512, bm, bn, As, Bs);
}

__global__ __launch_bounds__(512) void k_gp(MegaP P) {
    __shared__ __align__(16) u16 As[8192];
    __shared__ __align__(16) u16 Bs[16384];
    gemm_tile<64, true>(P.Abuf, P.Wpt, P.bpf, P.outF, P.N, 64, blockIdx.x, 0, As, Bs);
}

// ---------------- GATv2 edge kernel: one wave per dst node; self-loop inline ----------------

__global__ __launch_bounds__(256) void k_edge(const int* __restrict__ cnt,
                                              const u16* __restrict__ slot,
                                              const u16* __restrict__ XLR,
                                              const float* __restrict__ att,
                                              const float* __restrict__ bias,
                                              u16* __restrict__ H, int N) {
    int wid0 = blockIdx.x * 4 + (threadIdx.x >> 6);
    if (wid0 >= N) return;
    const int wid = __builtin_amdgcn_readfirstlane(wid0);
    const int l = threadIdx.x & 63;

    const float LOG2E = 1.4426950408889634f;
    float4 a4 = *(const float4*)(att + l * 4);
    a4.x *= LOG2E; a4.y *= LOG2E; a4.z *= LOG2E; a4.w *= LOG2E;
    float4 bb = *(const float4*)(bias + l * 4);
    const char* Xb = (const char*)XLR;
    const int lofs = l << 3;

    uint2 xr = *(const uint2*)(Xb + ((size_t)wid << 10) + 512 + lofs);
    float r0 = __uint_as_float(xr.x << 16), r1 = __uint_as_float(xr.x & 0xffff0000u);
    float r2 = __uint_as_float(xr.y << 16), r3 = __uint_as_float(xr.y & 0xffff0000u);

    const u16* sl = slot + ((size_t)wid << 6);
    int deg = cnt[wid];
    if (deg > 64) deg = 64;
    float s = 0.f, o0 = 0.f, o1 = 0.f, o2 = 0.f, o3 = 0.f;

    auto edge1 = [&](uint2 wv) {
        float c0 = __uint_as_float(wv.x << 16), c1 = __uint_as_float(wv.x & 0xffff0000u);
        float c2 = __uint_as_float(wv.y << 16), c3 = __uint_as_float(wv.y & 0xffff0000u);
        float t0 = c0 + r0, t1 = c1 + r1, t2 = c2 + r2, t3 = c3 + r3;
        t0 = fmaf(-0.8f, fminf(t0, 0.f), t0);
        t1 = fmaf(-0.8f, fminf(t1, 0.f), t1);
        t2 = fmaf(-0.8f, fminf(t2, 0.f), t2);
        t3 = fmaf(-0.8f, fminf(t3, 0.f), t3);
        float p = t0 * a4.x; p = fmaf(t1, a4.y, p); p = fmaf(t2, a4.z, p); p = fmaf(t3, a4.w, p);
        p = dpp_add<0xB1>(p);   // xor1
        p = dpp_add<0x4E>(p);   // xor2
        p = dpp_add<0x141>(p);  // row_half_mirror
        p = dpp_add<0x140>(p);  // row_mirror
        float e = exp2_hw(p);
        s += e;
        o0 = fmaf(e, c0, o0); o1 = fmaf(e, c1, o1);
        o2 = fmaf(e, c2, o2); o3 = fmaf(e, c3, o3);
    };

    // self-loop (u = wid), never stored in slot
    {
        uint2 w0 = *(const uint2*)(Xb + ((size_t)wid << 10) + lofs);
        edge1(w0);
    }

    int i = 0;
    for (; i + 8 <= deg; i += 8) {
        int u0 = __builtin_amdgcn_readfirstlane(sl[i]);
        int u1 = __builtin_amdgcn_readfirstlane(sl[i + 1]);
        int u2 = __builtin_amdgcn_readfirstlane(sl[i + 2]);
        int u3 = __builtin_amdgcn_readfirstlane(sl[i + 3]);
        int u4 = __builtin_amdgcn_readfirstlane(sl[i + 4]);
        int u5 = __builtin_amdgcn_readfirstlane(sl[i + 5]);
        int u6 = __builtin_amdgcn_readfirstlane(sl[i + 6]);
        int u7 = __builtin_amdgcn_readfirstlane(sl[i + 7]);
        uint2 w0 = *(const uint2*)(Xb + ((size_t)u0 << 10) + lofs);
        uint2 w1 = *(const uint2*)(Xb + ((size_t)u1 << 10) + lofs);
        uint2 w2 = *(const uint2*)(Xb + ((size_t)u2 << 10) + lofs);
        uint2 w3 = *(const uint2*)(Xb + ((size_t)u3 << 10) + lofs);
        uint2 w4 = *(const uint2*)(Xb + ((size_t)u4 << 10) + lofs);
        uint2 w5 = *(const uint2*)(Xb + ((size_t)u5 << 10) + lofs);
        uint2 w6 = *(const uint2*)(Xb + ((size_t)u6 << 10) + lofs);
        uint2 w7 = *(const uint2*)(Xb + ((size_t)u7 << 10) + lofs);
        edge1(w0); edge1(w1); edge1(w2); edge1(w3);
        edge1(w4); edge1(w5); edge1(w6); edge1(w7);
    }
    for (; i + 4 <= deg; i += 4) {
        int u0 = __builtin_amdgcn_readfirstlane(sl[i]);
        int u1 = __builtin_amdgcn_readfirstlane(sl[i + 1]);
        int u2 = __builtin_amdgcn_readfirstlane(sl[i + 2]);
        int u3 = __builtin_amdgcn_readfirstlane(sl[i + 3]);
        uint2 w0 = *(const uint2*)(Xb + ((size_t)u0 << 10) + lofs);
        uint2 w1 = *(const uint2*)(Xb + ((size_t)u1 << 10) + lofs);
        uint2 w2 = *(const uint2*)(Xb + ((size_t)u2 << 10) + lofs);
        uint2 w3 = *(const uint2*)(Xb + ((size_t)u3 << 10) + lofs);
        edge1(w0); edge1(w1); edge1(w2); edge1(w3);
    }
    for (; i < deg; ++i) {
        int u0 = __builtin_amdgcn_readfirstlane(sl[i]);
        uint2 w0 = *(const uint2*)(Xb + ((size_t)u0 << 10) + lofs);
        edge1(w0);
    }

    float inv = 1.f / s;
    o0 = fmaxf(fmaf(o0, inv, bb.x), 0.f);
    o1 = fmaxf(fmaf(o1, inv, bb.y), 0.f);
    o2 = fmaxf(fmaf(o2, inv, bb.z), 0.f);
    o3 = fmaxf(fmaf(o3, inv, bb.w), 0.f);
    ushort4 w4 = {f2bf(o0), f2bf(o1), f2bf(o2), f2bf(o3)};
    *(ushort4*)(H + ((size_t)wid << 8) + l * 4) = w4;
}

// ---------------- launcher ----------------

extern "C" void kernel_launch(void* const* d_in, const int* in_sizes, int n_in,
                              void* d_out, int out_size, void* d_ws, size_t ws_size,
                              hipStream_t stream) {
    MegaP P;
    P.x     = (const float*)d_in[0];
    P.ei    = (const int*)d_in[1];
    P.W1l   = (const float*)d_in[2];  P.b1l  = (const float*)d_in[3];
    P.W1r   = (const float*)d_in[4];  P.b1r  = (const float*)d_in[5];
    P.att1  = (const float*)d_in[6];  P.bias1 = (const float*)d_in[7];
    P.W2l   = (const float*)d_in[8];  P.b2l  = (const float*)d_in[9];
    P.W2r   = (const float*)d_in[10]; P.b2r  = (const float*)d_in[11];
    P.att2  = (const float*)d_in[12]; P.bias2 = (const float*)d_in[13];
    P.Wp1   = (const float*)d_in[14]; P.bp1  = (const float*)d_in[15];
    P.Wp2   = (const float*)d_in[16]; P.bp2  = (const float*)d_in[17];

    const int N = in_sizes[0] / 256;
    const int E = in_sizes[1] / 2;
    const int Mpad = ((N + 127) / 128) * 128;

    char* ws = (char*)d_ws;
    size_t o = 0;
    auto alloc = [&](size_t b) { char* p = ws + o; o = (o + b + 255) & ~(size_t)255; return p; };
    P.Xbf    = (u16*)alloc((size_t)Mpad * 256 * 2);
    P.Abuf   = (u16*)alloc((size_t)Mpad * 256 * 2);
    P.XLR    = (u16*)alloc((size_t)Mpad * 512 * 2);
    P.WB1    = (u16*)alloc(512 * 256 * 2);
    P.WB2    = (u16*)alloc(512 * 256 * 2);
    P.Wpt    = (u16*)alloc(64 * 256 * 2);
    P.bc1    = (float*)alloc(512 * 4);
    P.bc2    = (float*)alloc(512 * 4);
    P.bpf    = (float*)alloc(64 * 4);
    P.cnt    = (int*)alloc((size_t)N * 4);
    P.slot   = (u16*)alloc((size_t)N * 64 * 2);
    P.outF   = (float*)d_out;
    P.N = N; P.E = E; P.Mpad = Mpad; P.Mt = Mpad / 128;

    hipMemsetAsync(P.cnt, 0, (size_t)N * 4, stream);
    if (Mpad > N) {  // pad rows read by GEMMs; keep them finite
        hipMemsetAsync(P.Xbf + (size_t)N * 256, 0, (size_t)(Mpad - N) * 256 * 2, stream);
        hipMemsetAsync(P.Abuf + (size_t)N * 256, 0, (size_t)(Mpad - N) * 256 * 2, stream);
    }

    // prep: weights + bias + postW + x->bf16 + XCD-sharded scatter
    const int nCvt = (N * 64 + 255) / 256;
    const int nScat = ((E + 255) / 256) * 8;
    k_prep<<<1024 + 64 + 4 + nCvt + nScat, 256, 0, stream>>>(P);

    const int ntile = P.Mt * 4;
    const int egrid = (N + 3) / 4;
    k_g1<<<ntile, 512, 0, stream>>>(P);
    k_edge<<<egrid, 256, 0, stream>>>(P.cnt, P.slot, P.XLR, P.att1, P.bias1, P.Abuf, N);
    k_g2<<<ntile, 512, 0, stream>>>(P);
    k_edge<<<egrid, 256, 0, stream>>>(P.cnt, P.slot, P.XLR, P.att2, P.bias2, P.Abuf, N);
    k_gp<<<P.Mt, 512, 0, stream>>>(P);
}

// Round 16
// 247.786 us; speedup vs baseline: 1.1116x; 1.0363x over previous
//
#include <hip/hip_runtime.h>

typedef unsigned short u16;
typedef short bf16x8 __attribute__((ext_vector_type(8)));
typedef float f32x4 __attribute__((ext_vector_type(4)));
typedef float f32x2 __attribute__((ext_vector_type(2)));

__device__ __forceinline__ u16 f2bf(float f) {
    unsigned u = __float_as_uint(f);
    return (u16)((u + 0x7fffu + ((u >> 16) & 1u)) >> 16);
}
__device__ __forceinline__ float exp2_hw(float x) {
    float r;
    asm("v_exp_f32 %0, %1" : "=v"(r) : "v"(x));
    return r;
}
template <int CTRL>
__device__ __forceinline__ float dpp_add(float p) {
    int t = __builtin_amdgcn_update_dpp(0, __float_as_int(p), CTRL, 0xf, 0xf, true);
    return p + __int_as_float(t);
}
__device__ __forceinline__ void gload_lds16(const u16* g, u16* lds) {
    __builtin_amdgcn_global_load_lds((const __attribute__((address_space(1))) void*)g,
                                     (__attribute__((address_space(3))) void*)lds, 16, 0, 0);
}

struct MegaP {
    const float* x; const int* ei;
    const float *W1l, *b1l, *W1r, *b1r, *att1, *bias1;
    const float *W2l, *b2l, *W2r, *b2r, *att2, *bias2;
    const float *Wp1, *bp1, *Wp2, *bp2;
    u16 *Abuf, *XLR, *WB1, *WB2, *Wpt;
    float *bc1, *bc2, *bpf;
    int *cnt; u16 *slot;
    float* outF;
    int N, E, Mpad, Mt;
};

// ---------------- GEMM tile (r13 structure): one 128 x BN tile of C = A[M,256] @ Bt^T + bias ----
// B panel (BN x 256) LDS-resident (XOR chunk swizzle); A staged per BK=64
// (global_load_lds for bf16; reg-stage+cvt for f32). 8 waves (2x4), wave tile 64 x (NRF*16).

template <bool AF32, int BN, bool F32OUT>
__device__ __forceinline__ void gemm_tile(const void* __restrict__ Av, const u16* __restrict__ Bt,
                                          const float* __restrict__ bias, void* __restrict__ out,
                                          int M, int Nout, int bm, int bn, u16* As, u16* Bs) {
    constexpr int K = 256;
    constexpr int NRF = BN / 64;
    const int tid = threadIdx.x;
    const int l = tid & 63;
    const int w = tid >> 6;
    const int wm = w >> 2, wn = w & 3;
    const int lrow = l & 15, lk = l >> 4;
    const int wbase = tid & ~63;

#pragma unroll
    for (int it = 0; it < BN / 16; ++it) {  // stage B panel (XOR chunk swizzle)
        int c = it * 512 + tid;
        int col = c >> 5, kc = c & 31;
        bf16x8 v = *(const bf16x8*)(Bt + (size_t)(bn * BN + col) * K + kc * 8);
        *(bf16x8*)(Bs + col * K + ((kc ^ (col & 7)) * 8)) = v;
    }

    auto stageA = [&](int ks) {
        if (AF32) {
            const float* A32 = (const float*)Av;
#pragma unroll
            for (int it = 0; it < 2; ++it) {
                int c = it * 512 + tid;
                int row = c >> 3, seg = c & 7;
                int grow = bm * 128 + row;
                if (grow > M - 1) grow = M - 1;
                const float* sp = A32 + (size_t)grow * K + ks * 64 + seg * 8;
                float4 v0 = *(const float4*)sp;
                float4 v1 = *(const float4*)(sp + 4);
                bf16x8 pk;
                pk[0] = (short)f2bf(v0.x); pk[1] = (short)f2bf(v0.y);
                pk[2] = (short)f2bf(v0.z); pk[3] = (short)f2bf(v0.w);
                pk[4] = (short)f2bf(v1.x); pk[5] = (short)f2bf(v1.y);
                pk[6] = (short)f2bf(v1.z); pk[7] = (short)f2bf(v1.w);
                *(bf16x8*)(As + row * 64 + ((seg ^ (row & 7)) * 8)) = pk;
            }
        } else {
            const u16* Abf = (const u16*)Av;
#pragma unroll
            for (int it = 0; it < 2; ++it) {
                int c = it * 512 + tid;
                int row = c >> 3, seg = c & 7;
                int ssrc = seg ^ (row & 7);
                gload_lds16(Abf + (size_t)(bm * 128 + row) * K + ks * 64 + ssrc * 8,
                            As + (size_t)(it * 512 + wbase) * 8);
            }
        }
    };

    f32x4 acc[4][NRF];
#pragma unroll
    for (int m = 0; m < 4; ++m)
#pragma unroll
        for (int n = 0; n < NRF; ++n) acc[m][n] = (f32x4){0.f, 0.f, 0.f, 0.f};

    stageA(0);
    __syncthreads();

    for (int ks = 0; ks < 4; ++ks) {
#pragma unroll
        for (int h = 0; h < 2; ++h) {
            bf16x8 av[4], bv[NRF];
#pragma unroll
            for (int m = 0; m < 4; ++m) {
                int row = wm * 64 + m * 16 + lrow;
                int seg = ((h * 4 + lk) ^ (row & 7));
                av[m] = *(const bf16x8*)(As + row * 64 + seg * 8);
            }
#pragma unroll
            for (int n = 0; n < NRF; ++n) {
                int col = wn * (NRF * 16) + n * 16 + lrow;
                int kc = ks * 8 + h * 4 + lk;
                bv[n] = *(const bf16x8*)(Bs + col * K + ((kc ^ (col & 7)) * 8));
            }
#pragma unroll
            for (int m = 0; m < 4; ++m)
#pragma unroll
                for (int n = 0; n < NRF; ++n)
                    acc[m][n] = __builtin_amdgcn_mfma_f32_16x16x32_bf16(av[m], bv[n], acc[m][n], 0, 0, 0);
        }
        if (ks < 3) {
            __syncthreads();
            stageA(ks + 1);
            __syncthreads();
        }
    }

    float bl[NRF];
#pragma unroll
    for (int n = 0; n < NRF; ++n) bl[n] = bias[bn * BN + wn * (NRF * 16) + n * 16 + lrow];

#pragma unroll
    for (int m = 0; m < 4; ++m) {
        int grow = bm * 128 + wm * 64 + m * 16 + lk * 4;
#pragma unroll
        for (int j = 0; j < 4; ++j) {
            if (grow + j < M) {
#pragma unroll
                for (int n = 0; n < NRF; ++n) {
                    int col = bn * BN + wn * (NRF * 16) + n * 16 + lrow;
                    float v = acc[m][n][j] + bl[n];
                    if (F32OUT)
                        ((float*)out)[(size_t)(grow + j) * Nout + col] = v;
                    else
                        ((u16*)out)[(size_t)(grow + j) * Nout + col] = f2bf(v);
                }
            }
        }
    }
}

// XCD-aware tile map for ct=4 col-tiles: all 4 col-tiles of one bm get the same d%8.
__device__ __forceinline__ void tile_map4(int d, int Mt, int& bm, int& bn) {
    int nfull = (Mt & ~7) * 4;
    if (d < nfull) {
        int g = d >> 5, r = d & 31;
        bm = g * 8 + (r & 7);
        bn = r >> 3;
    } else {
        int idx = d - nfull;
        bm = (Mt & ~7) + (idx >> 2);
        bn = idx & 3;
    }
}

// ---------------- prep kernel: weights + postW + bias only (small, fast) ----------------

__global__ __launch_bounds__(256) void k_prep(MegaP P) {
    const int c0 = 1024, c1 = c0 + 64;
    int b = blockIdx.x;
    int tid = threadIdx.x;
    if (b < c0) {  // weight transpose: WB = [Wl^T ; Wr^T] bf16
        int n = b & 255, m = b >> 8;
        const float* W = (m == 0) ? P.W1l : (m == 1) ? P.W1r : (m == 2) ? P.W2l : P.W2r;
        u16* dst = (m < 2) ? P.WB1 : P.WB2;
        dst[(size_t)((m & 1) * 256 + n) * 256 + tid] = f2bf(W[(size_t)tid * 256 + n]);
    } else if (b < c1) {  // fused post-MLP weight
        int j = b - c0;
        float a = 0.f;
        for (int k = 0; k < 64; ++k) a += P.Wp1[tid * 64 + k] * P.Wp2[k * 64 + j];
        P.Wpt[j * 256 + tid] = f2bf(a);
        if (tid == 0) {
            float bb = P.bp2[j];
            for (int k = 0; k < 64; ++k) bb += P.bp1[k] * P.Wp2[k * 64 + j];
            P.bpf[j] = bb;
        }
    } else {  // bias concat
        int m = b - c1;
        const float* s = (m == 0) ? P.b1l : (m == 1) ? P.b1r : (m == 2) ? P.b2l : P.b2r;
        float* d = (m < 2) ? P.bc1 : P.bc2;
        d[(m & 1) * 256 + tid] = s[tid];
    }
}

// ---------------- k_g1: GEMM1 tiles FIRST, XCD-sharded scatter tail ----------------
// GEMM blocks fill the machine; latency-bound scatter blocks backfill as tiles retire
// (r11 failed with scatter first: it drained serially before GEMM became resident).

__global__ __launch_bounds__(512) void k_g1(MegaP P, int ntile) {
    __shared__ __align__(16) u16 As[8192];
    __shared__ __align__(16) u16 Bs[32768];
    if ((int)blockIdx.x < ntile) {
        int bm, bn;
        tile_map4(blockIdx.x, P.Mt, bm, bn);
        gemm_tile<true, 128, false>(P.x, P.WB1, P.bc1, P.XLR, P.N, 512, bm, bn, As, Bs);
    } else {
        const int N = P.N, E = P.E;
        int bi = (int)blockIdx.x - ntile;
        int xcd = bi & 7;
        int e = (bi >> 3) * 512 + threadIdx.x;
        if (e < E) {
            int dst = P.ei[E + e];
            int S = (N + 7) >> 3;
            if ((unsigned)(dst - xcd * S) < (unsigned)S) {
                int src = P.ei[e];
                int p = atomicAdd(P.cnt + dst, 1);
                if (p < 64) P.slot[((size_t)dst << 6) + p] = (u16)src;
            }
        }
    }
}

__global__ __launch_bounds__(512) void k_g2(MegaP P) {
    __shared__ __align__(16) u16 As[8192];
    __shared__ __align__(16) u16 Bs[32768];
    int bm, bn;
    tile_map4(blockIdx.x, P.Mt, bm, bn);
    gemm_tile<false, 128, false>(P.Abuf, P.WB2, P.bc2, P.XLR, P.N, 512, bm, bn, As, Bs);
}

__global__ __launch_bounds__(512) void k_gp(MegaP P) {
    __shared__ __align__(16) u16 As[8192];
    __shared__ __align__(16) u16 Bs[16384];
    gemm_tile<false, 64, true>(P.Abuf, P.Wpt, P.bpf, P.outF, P.N, 64, blockIdx.x, 0, As, Bs);
}

// ---------------- GATv2 edge kernel: one wave per dst node; packed-f32 channel math ----------
// lrelu(t) = max(t, 0.2t) (exact identity); channel ops on f32x2 -> v_pk_add/mul/fma.

__global__ __launch_bounds__(256) void k_edge(const int* __restrict__ cnt,
                                              const u16* __restrict__ slot,
                                              const u16* __restrict__ XLR,
                                              const float* __restrict__ att,
                                              const float* __restrict__ bias,
                                              u16* __restrict__ H, int N) {
    int wid0 = blockIdx.x * 4 + (threadIdx.x >> 6);
    if (wid0 >= N) return;
    const int wid = __builtin_amdgcn_readfirstlane(wid0);
    const int l = threadIdx.x & 63;

    const float LOG2E = 1.4426950408889634f;
    float4 a4 = *(const float4*)(att + l * 4);
    f32x2 aA = {a4.x * LOG2E, a4.y * LOG2E};
    f32x2 aB = {a4.z * LOG2E, a4.w * LOG2E};
    float4 bb = *(const float4*)(bias + l * 4);
    const char* Xb = (const char*)XLR;
    const int lofs = l << 3;

    uint2 xr = *(const uint2*)(Xb + ((size_t)wid << 10) + 512 + lofs);
    f32x2 rA = {__uint_as_float(xr.x << 16), __uint_as_float(xr.x & 0xffff0000u)};
    f32x2 rB = {__uint_as_float(xr.y << 16), __uint_as_float(xr.y & 0xffff0000u)};

    const u16* sl = slot + ((size_t)wid << 6);
    int deg = cnt[wid];
    if (deg > 64) deg = 64;
    float s = 0.f;
    f32x2 oA = {0.f, 0.f}, oB = {0.f, 0.f};

    auto edge1 = [&](uint2 wv) {
        f32x2 cA = {__uint_as_float(wv.x << 16), __uint_as_float(wv.x & 0xffff0000u)};
        f32x2 cB = {__uint_as_float(wv.y << 16), __uint_as_float(wv.y & 0xffff0000u)};
        f32x2 tA = cA + rA, tB = cB + rB;          // pk_add
        f32x2 uA = tA * 0.2f, uB = tB * 0.2f;      // pk_mul
        tA.x = fmaxf(tA.x, uA.x); tA.y = fmaxf(tA.y, uA.y);  // lrelu = max(t, 0.2t)
        tB.x = fmaxf(tB.x, uB.x); tB.y = fmaxf(tB.y, uB.y);
        f32x2 pd = tA * aA;                        // pk_mul
        pd = __builtin_elementwise_fma(tB, aB, pd);  // pk_fma
        float p = pd.x + pd.y;
        p = dpp_add<0xB1>(p);   // xor1
        p = dpp_add<0x4E>(p);   // xor2
        p = dpp_add<0x141>(p);  // row_half_mirror
        p = dpp_add<0x140>(p);  // row_mirror
        float e = exp2_hw(p);
        s += e;
        f32x2 ee = {e, e};
        oA = __builtin_elementwise_fma(ee, cA, oA);  // pk_fma
        oB = __builtin_elementwise_fma(ee, cB, oB);
    };

    // self-loop (u = wid), never stored in slot
    {
        uint2 w0 = *(const uint2*)(Xb + ((size_t)wid << 10) + lofs);
        edge1(w0);
    }

    int i = 0;
    for (; i + 8 <= deg; i += 8) {
        int u0 = __builtin_amdgcn_readfirstlane(sl[i]);
        int u1 = __builtin_amdgcn_readfirstlane(sl[i + 1]);
        int u2 = __builtin_amdgcn_readfirstlane(sl[i + 2]);
        int u3 = __builtin_amdgcn_readfirstlane(sl[i + 3]);
        int u4 = __builtin_amdgcn_readfirstlane(sl[i + 4]);
        int u5 = __builtin_amdgcn_readfirstlane(sl[i + 5]);
        int u6 = __builtin_amdgcn_readfirstlane(sl[i + 6]);
        int u7 = __builtin_amdgcn_readfirstlane(sl[i + 7]);
        uint2 w0 = *(const uint2*)(Xb + ((size_t)u0 << 10) + lofs);
        uint2 w1 = *(const uint2*)(Xb + ((size_t)u1 << 10) + lofs);
        uint2 w2 = *(const uint2*)(Xb + ((size_t)u2 << 10) + lofs);
        uint2 w3 = *(const uint2*)(Xb + ((size_t)u3 << 10) + lofs);
        uint2 w4 = *(const uint2*)(Xb + ((size_t)u4 << 10) + lofs);
        uint2 w5 = *(const uint2*)(Xb + ((size_t)u5 << 10) + lofs);
        uint2 w6 = *(const uint2*)(Xb + ((size_t)u6 << 10) + lofs);
        uint2 w7 = *(const uint2*)(Xb + ((size_t)u7 << 10) + lofs);
        edge1(w0); edge1(w1); edge1(w2); edge1(w3);
        edge1(w4); edge1(w5); edge1(w6); edge1(w7);
    }
    for (; i + 4 <= deg; i += 4) {
        int u0 = __builtin_amdgcn_readfirstlane(sl[i]);
        int u1 = __builtin_amdgcn_readfirstlane(sl[i + 1]);
        int u2 = __builtin_amdgcn_readfirstlane(sl[i + 2]);
        int u3 = __builtin_amdgcn_readfirstlane(sl[i + 3]);
        uint2 w0 = *(const uint2*)(Xb + ((size_t)u0 << 10) + lofs);
        uint2 w1 = *(const uint2*)(Xb + ((size_t)u1 << 10) + lofs);
        uint2 w2 = *(const uint2*)(Xb + ((size_t)u2 << 10) + lofs);
        uint2 w3 = *(const uint2*)(Xb + ((size_t)u3 << 10) + lofs);
        edge1(w0); edge1(w1); edge1(w2); edge1(w3);
    }
    for (; i < deg; ++i) {
        int u0 = __builtin_amdgcn_readfirstlane(sl[i]);
        uint2 w0 = *(const uint2*)(Xb + ((size_t)u0 << 10) + lofs);
        edge1(w0);
    }

    float inv = 1.f / s;
    float o0 = fmaxf(fmaf(oA.x, inv, bb.x), 0.f);
    float o1 = fmaxf(fmaf(oA.y, inv, bb.y), 0.f);
    float o2 = fmaxf(fmaf(oB.x, inv, bb.z), 0.f);
    float o3 = fmaxf(fmaf(oB.y, inv, bb.w), 0.f);
    ushort4 w4 = {f2bf(o0), f2bf(o1), f2bf(o2), f2bf(o3)};
    *(ushort4*)(H + ((size_t)wid << 8) + l * 4) = w4;
}

// ---------------- launcher ----------------

extern "C" void kernel_launch(void* const* d_in, const int* in_sizes, int n_in,
                              void* d_out, int out_size, void* d_ws, size_t ws_size,
                              hipStream_t stream) {
    MegaP P;
    P.x     = (const float*)d_in[0];
    P.ei    = (const int*)d_in[1];
    P.W1l   = (const float*)d_in[2];  P.b1l  = (const float*)d_in[3];
    P.W1r   = (const float*)d_in[4];  P.b1r  = (const float*)d_in[5];
    P.att1  = (const float*)d_in[6];  P.bias1 = (const float*)d_in[7];
    P.W2l   = (const float*)d_in[8];  P.b2l  = (const float*)d_in[9];
    P.W2r   = (const float*)d_in[10]; P.b2r  = (const float*)d_in[11];
    P.att2  = (const float*)d_in[12]; P.bias2 = (const float*)d_in[13];
    P.Wp1   = (const float*)d_in[14]; P.bp1  = (const float*)d_in[15];
    P.Wp2   = (const float*)d_in[16]; P.bp2  = (const float*)d_in[17];

    const int N = in_sizes[0] / 256;
    const int E = in_sizes[1] / 2;
    const int Mpad = ((N + 127) / 128) * 128;

    char* ws = (char*)d_ws;
    size_t o = 0;
    auto alloc = [&](size_t b) { char* p = ws + o; o = (o + b + 255) & ~(size_t)255; return p; };
    P.Abuf   = (u16*)alloc((size_t)Mpad * 256 * 2);
    P.XLR    = (u16*)alloc((size_t)Mpad * 512 * 2);
    P.WB1    = (u16*)alloc(512 * 256 * 2);
    P.WB2    = (u16*)alloc(512 * 256 * 2);
    P.Wpt    = (u16*)alloc(64 * 256 * 2);
    P.bc1    = (float*)alloc(512 * 4);
    P.bc2    = (float*)alloc(512 * 4);
    P.bpf    = (float*)alloc(64 * 4);
    P.cnt    = (int*)alloc((size_t)N * 4);
    P.slot   = (u16*)alloc((size_t)N * 64 * 2);
    P.outF   = (float*)d_out;
    P.N = N; P.E = E; P.Mpad = Mpad; P.Mt = Mpad / 128;

    hipMemsetAsync(P.cnt, 0, (size_t)N * 4, stream);
    if (Mpad > N)  // pad rows of Abuf read by g2/gp's gload_lds path
        hipMemsetAsync(P.Abuf + (size_t)N * 256, 0, (size_t)(Mpad - N) * 256 * 2, stream);

    // prep: weights + postW + bias (small)
    k_prep<<<1024 + 64 + 4, 256, 0, stream>>>(P);

    // g1: GEMM tiles first, XCD-sharded scatter tail (overlapped)
    const int ntile = P.Mt * 4;
    const int nScat = ((E + 511) / 512) * 8;
    k_g1<<<ntile + nScat, 512, 0, stream>>>(P, ntile);

    const int egrid = (N + 3) / 4;
    k_edge<<<egrid, 256, 0, stream>>>(P.cnt, P.slot, P.XLR, P.att1, P.bias1, P.Abuf, N);
    k_g2<<<ntile, 512, 0, stream>>>(P);
    k_edge<<<egrid, 256, 0, stream>>>(P.cnt, P.slot, P.XLR, P.att2, P.bias2, P.Abuf, N);
    k_gp<<<P.Mt, 512, 0, stream>>>(P);
}

// Round 17
// 247.727 us; speedup vs baseline: 1.1118x; 1.0002x over previous
//
#include <hip/hip_runtime.h>

typedef unsigned short u16;
typedef short bf16x8 __attribute__((ext_vector_type(8)));
typedef float f32x4 __attribute__((ext_vector_type(4)));
typedef float f32x2 __attribute__((ext_vector_type(2)));

__device__ __forceinline__ u16 f2bf(float f) {
    unsigned u = __float_as_uint(f);
    return (u16)((u + 0x7fffu + ((u >> 16) & 1u)) >> 16);
}
__device__ __forceinline__ float exp2_hw(float x) {
    float r;
    asm("v_exp_f32 %0, %1" : "=v"(r) : "v"(x));
    return r;
}
template <int CTRL>
__device__ __forceinline__ float dpp_add(float p) {
    int t = __builtin_amdgcn_update_dpp(0, __float_as_int(p), CTRL, 0xf, 0xf, true);
    return p + __int_as_float(t);
}
__device__ __forceinline__ void gload_lds16(const u16* g, u16* lds) {
    __builtin_amdgcn_global_load_lds((const __attribute__((address_space(1))) void*)g,
                                     (__attribute__((address_space(3))) void*)lds, 16, 0, 0);
}

struct MegaP {
    const float* x; const int* ei;
    const float *W1l, *b1l, *W1r, *b1r, *att1, *bias1;
    const float *W2l, *b2l, *W2r, *b2r, *att2, *bias2;
    const float *Wp1, *bp1, *Wp2, *bp2;
    u16 *Abuf, *XLR, *WB1, *WB2, *Wpt;
    float *bc1, *bc2, *bpf;
    int *cnt; u16 *slot;
    float* outF;
    int N, E, Mpad, Mt;
};

// ---------------- GEMM tile (r13 structure): one 128 x BN tile of C = A[M,256] @ Bt^T + bias ----
// B panel (BN x 256) LDS-resident (XOR chunk swizzle); A staged per BK=64
// (global_load_lds for bf16; reg-stage+cvt for f32). 8 waves (2x4), wave tile 64 x (NRF*16).

template <bool AF32, int BN, bool F32OUT>
__device__ __forceinline__ void gemm_tile(const void* __restrict__ Av, const u16* __restrict__ Bt,
                                          const float* __restrict__ bias, void* __restrict__ out,
                                          int M, int Nout, int bm, int bn, u16* As, u16* Bs) {
    constexpr int K = 256;
    constexpr int NRF = BN / 64;
    const int tid = threadIdx.x;
    const int l = tid & 63;
    const int w = tid >> 6;
    const int wm = w >> 2, wn = w & 3;
    const int lrow = l & 15, lk = l >> 4;
    const int wbase = tid & ~63;

#pragma unroll
    for (int it = 0; it < BN / 16; ++it) {  // stage B panel (XOR chunk swizzle)
        int c = it * 512 + tid;
        int col = c >> 5, kc = c & 31;
        bf16x8 v = *(const bf16x8*)(Bt + (size_t)(bn * BN + col) * K + kc * 8);
        *(bf16x8*)(Bs + col * K + ((kc ^ (col & 7)) * 8)) = v;
    }

    auto stageA = [&](int ks) {
        if (AF32) {
            const float* A32 = (const float*)Av;
#pragma unroll
            for (int it = 0; it < 2; ++it) {
                int c = it * 512 + tid;
                int row = c >> 3, seg = c & 7;
                int grow = bm * 128 + row;
                if (grow > M - 1) grow = M - 1;
                const float* sp = A32 + (size_t)grow * K + ks * 64 + seg * 8;
                float4 v0 = *(const float4*)sp;
                float4 v1 = *(const float4*)(sp + 4);
                bf16x8 pk;
                pk[0] = (short)f2bf(v0.x); pk[1] = (short)f2bf(v0.y);
                pk[2] = (short)f2bf(v0.z); pk[3] = (short)f2bf(v0.w);
                pk[4] = (short)f2bf(v1.x); pk[5] = (short)f2bf(v1.y);
                pk[6] = (short)f2bf(v1.z); pk[7] = (short)f2bf(v1.w);
                *(bf16x8*)(As + row * 64 + ((seg ^ (row & 7)) * 8)) = pk;
            }
        } else {
            const u16* Abf = (const u16*)Av;
#pragma unroll
            for (int it = 0; it < 2; ++it) {
                int c = it * 512 + tid;
                int row = c >> 3, seg = c & 7;
                int ssrc = seg ^ (row & 7);
                gload_lds16(Abf + (size_t)(bm * 128 + row) * K + ks * 64 + ssrc * 8,
                            As + (size_t)(it * 512 + wbase) * 8);
            }
        }
    };

    f32x4 acc[4][NRF];
#pragma unroll
    for (int m = 0; m < 4; ++m)
#pragma unroll
        for (int n = 0; n < NRF; ++n) acc[m][n] = (f32x4){0.f, 0.f, 0.f, 0.f};

    stageA(0);
    __syncthreads();

    for (int ks = 0; ks < 4; ++ks) {
#pragma unroll
        for (int h = 0; h < 2; ++h) {
            bf16x8 av[4], bv[NRF];
#pragma unroll
            for (int m = 0; m < 4; ++m) {
                int row = wm * 64 + m * 16 + lrow;
                int seg = ((h * 4 + lk) ^ (row & 7));
                av[m] = *(const bf16x8*)(As + row * 64 + seg * 8);
            }
#pragma unroll
            for (int n = 0; n < NRF; ++n) {
                int col = wn * (NRF * 16) + n * 16 + lrow;
                int kc = ks * 8 + h * 4 + lk;
                bv[n] = *(const bf16x8*)(Bs + col * K + ((kc ^ (col & 7)) * 8));
            }
#pragma unroll
            for (int m = 0; m < 4; ++m)
#pragma unroll
                for (int n = 0; n < NRF; ++n)
                    acc[m][n] = __builtin_amdgcn_mfma_f32_16x16x32_bf16(av[m], bv[n], acc[m][n], 0, 0, 0);
        }
        if (ks < 3) {
            __syncthreads();
            stageA(ks + 1);
            __syncthreads();
        }
    }

    float bl[NRF];
#pragma unroll
    for (int n = 0; n < NRF; ++n) bl[n] = bias[bn * BN + wn * (NRF * 16) + n * 16 + lrow];

#pragma unroll
    for (int m = 0; m < 4; ++m) {
        int grow = bm * 128 + wm * 64 + m * 16 + lk * 4;
#pragma unroll
        for (int j = 0; j < 4; ++j) {
            if (grow + j < M) {
#pragma unroll
                for (int n = 0; n < NRF; ++n) {
                    int col = bn * BN + wn * (NRF * 16) + n * 16 + lrow;
                    float v = acc[m][n][j] + bl[n];
                    if (F32OUT)
                        ((float*)out)[(size_t)(grow + j) * Nout + col] = v;
                    else
                        ((u16*)out)[(size_t)(grow + j) * Nout + col] = f2bf(v);
                }
            }
        }
    }
}

// XCD-aware tile map for ct=4 col-tiles: all 4 col-tiles of one bm get the same d%8.
__device__ __forceinline__ void tile_map4(int d, int Mt, int& bm, int& bn) {
    int nfull = (Mt & ~7) * 4;
    if (d < nfull) {
        int g = d >> 5, r = d & 31;
        bm = g * 8 + (r & 7);
        bn = r >> 3;
    } else {
        int idx = d - nfull;
        bm = (Mt & ~7) + (idx >> 2);
        bn = idx & 3;
    }
}

// ---------------- prep kernel: weights + postW + bias + XCD-sharded scatter ----------------
// Scatter lives here (256-thread, ZERO LDS -> high occupancy). r16 proved putting it in the
// 80KB-LDS GEMM kernel crashes its occupancy (2 blocks/CU) and stretches it ~3x.

__global__ __launch_bounds__(256) void k_prep(MegaP P) {
    const int N = P.N, E = P.E;
    const int c0 = 1024, c1 = c0 + 64, c2 = c1 + 4;
    int b = blockIdx.x;
    int tid = threadIdx.x;
    if (b < c0) {  // weight transpose: WB = [Wl^T ; Wr^T] bf16
        int n = b & 255, m = b >> 8;
        const float* W = (m == 0) ? P.W1l : (m == 1) ? P.W1r : (m == 2) ? P.W2l : P.W2r;
        u16* dst = (m < 2) ? P.WB1 : P.WB2;
        dst[(size_t)((m & 1) * 256 + n) * 256 + tid] = f2bf(W[(size_t)tid * 256 + n]);
    } else if (b < c1) {  // fused post-MLP weight
        int j = b - c0;
        float a = 0.f;
        for (int k = 0; k < 64; ++k) a += P.Wp1[tid * 64 + k] * P.Wp2[k * 64 + j];
        P.Wpt[j * 256 + tid] = f2bf(a);
        if (tid == 0) {
            float bb = P.bp2[j];
            for (int k = 0; k < 64; ++k) bb += P.bp1[k] * P.Wp2[k * 64 + j];
            P.bpf[j] = bb;
        }
    } else if (b < c2) {  // bias concat
        int m = b - c1;
        const float* s = (m == 0) ? P.b1l : (m == 1) ? P.b1r : (m == 2) ? P.b2l : P.b2r;
        float* d = (m < 2) ? P.bc1 : P.bc2;
        d[(m & 1) * 256 + tid] = s[tid];
    } else {  // XCD-sharded scatter (self-loops NOT stored; edge kernel adds them inline)
        int bi = b - c2;
        int xcd = bi & 7;
        int e = (bi >> 3) * 256 + tid;
        if (e < E) {
            int dst = P.ei[E + e];
            int S = (N + 7) >> 3;
            if ((unsigned)(dst - xcd * S) < (unsigned)S) {
                int src = P.ei[e];
                int p = atomicAdd(P.cnt + dst, 1);
                if (p < 64) P.slot[((size_t)dst << 6) + p] = (u16)src;
            }
        }
    }
}

// ---------------- GEMM kernels ----------------

__global__ __launch_bounds__(512) void k_g1(MegaP P) {
    __shared__ __align__(16) u16 As[8192];
    __shared__ __align__(16) u16 Bs[32768];
    int bm, bn;
    tile_map4(blockIdx.x, P.Mt, bm, bn);
    gemm_tile<true, 128, false>(P.x, P.WB1, P.bc1, P.XLR, P.N, 512, bm, bn, As, Bs);
}

__global__ __launch_bounds__(512) void k_g2(MegaP P) {
    __shared__ __align__(16) u16 As[8192];
    __shared__ __align__(16) u16 Bs[32768];
    int bm, bn;
    tile_map4(blockIdx.x, P.Mt, bm, bn);
    gemm_tile<false, 128, false>(P.Abuf, P.WB2, P.bc2, P.XLR, P.N, 512, bm, bn, As, Bs);
}

__global__ __launch_bounds__(512) void k_gp(MegaP P) {
    __shared__ __align__(16) u16 As[8192];
    __shared__ __align__(16) u16 Bs[16384];
    gemm_tile<false, 64, true>(P.Abuf, P.Wpt, P.bpf, P.outF, P.N, 64, blockIdx.x, 0, As, Bs);
}

// ---------------- GATv2 edge kernel: one wave per dst node; packed-f32 channel math ----------
// lrelu(t) = max(t, 0.2t) (exact identity); channel ops on f32x2 -> v_pk_add/mul/fma.

__global__ __launch_bounds__(256) void k_edge(const int* __restrict__ cnt,
                                              const u16* __restrict__ slot,
                                              const u16* __restrict__ XLR,
                                              const float* __restrict__ att,
                                              const float* __restrict__ bias,
                                              u16* __restrict__ H, int N) {
    int wid0 = blockIdx.x * 4 + (threadIdx.x >> 6);
    if (wid0 >= N) return;
    const int wid = __builtin_amdgcn_readfirstlane(wid0);
    const int l = threadIdx.x & 63;

    const float LOG2E = 1.4426950408889634f;
    float4 a4 = *(const float4*)(att + l * 4);
    f32x2 aA = {a4.x * LOG2E, a4.y * LOG2E};
    f32x2 aB = {a4.z * LOG2E, a4.w * LOG2E};
    float4 bb = *(const float4*)(bias + l * 4);
    const char* Xb = (const char*)XLR;
    const int lofs = l << 3;

    uint2 xr = *(const uint2*)(Xb + ((size_t)wid << 10) + 512 + lofs);
    f32x2 rA = {__uint_as_float(xr.x << 16), __uint_as_float(xr.x & 0xffff0000u)};
    f32x2 rB = {__uint_as_float(xr.y << 16), __uint_as_float(xr.y & 0xffff0000u)};

    const u16* sl = slot + ((size_t)wid << 6);
    int deg = cnt[wid];
    if (deg > 64) deg = 64;
    float s = 0.f;
    f32x2 oA = {0.f, 0.f}, oB = {0.f, 0.f};

    auto edge1 = [&](uint2 wv) {
        f32x2 cA = {__uint_as_float(wv.x << 16), __uint_as_float(wv.x & 0xffff0000u)};
        f32x2 cB = {__uint_as_float(wv.y << 16), __uint_as_float(wv.y & 0xffff0000u)};
        f32x2 tA = cA + rA, tB = cB + rB;          // pk_add
        f32x2 uA = tA * 0.2f, uB = tB * 0.2f;      // pk_mul
        tA.x = fmaxf(tA.x, uA.x); tA.y = fmaxf(tA.y, uA.y);  // lrelu = max(t, 0.2t)
        tB.x = fmaxf(tB.x, uB.x); tB.y = fmaxf(tB.y, uB.y);
        f32x2 pd = tA * aA;                        // pk_mul
        pd = __builtin_elementwise_fma(tB, aB, pd);  // pk_fma
        float p = pd.x + pd.y;
        p = dpp_add<0xB1>(p);   // xor1
        p = dpp_add<0x4E>(p);   // xor2
        p = dpp_add<0x141>(p);  // row_half_mirror
        p = dpp_add<0x140>(p);  // row_mirror
        float e = exp2_hw(p);
        s += e;
        f32x2 ee = {e, e};
        oA = __builtin_elementwise_fma(ee, cA, oA);  // pk_fma
        oB = __builtin_elementwise_fma(ee, cB, oB);
    };

    // self-loop (u = wid), never stored in slot
    {
        uint2 w0 = *(const uint2*)(Xb + ((size_t)wid << 10) + lofs);
        edge1(w0);
    }

    int i = 0;
    for (; i + 8 <= deg; i += 8) {
        int u0 = __builtin_amdgcn_readfirstlane(sl[i]);
        int u1 = __builtin_amdgcn_readfirstlane(sl[i + 1]);
        int u2 = __builtin_amdgcn_readfirstlane(sl[i + 2]);
        int u3 = __builtin_amdgcn_readfirstlane(sl[i + 3]);
        int u4 = __builtin_amdgcn_readfirstlane(sl[i + 4]);
        int u5 = __builtin_amdgcn_readfirstlane(sl[i + 5]);
        int u6 = __builtin_amdgcn_readfirstlane(sl[i + 6]);
        int u7 = __builtin_amdgcn_readfirstlane(sl[i + 7]);
        uint2 w0 = *(const uint2*)(Xb + ((size_t)u0 << 10) + lofs);
        uint2 w1 = *(const uint2*)(Xb + ((size_t)u1 << 10) + lofs);
        uint2 w2 = *(const uint2*)(Xb + ((size_t)u2 << 10) + lofs);
        uint2 w3 = *(const uint2*)(Xb + ((size_t)u3 << 10) + lofs);
        uint2 w4 = *(const uint2*)(Xb + ((size_t)u4 << 10) + lofs);
        uint2 w5 = *(const uint2*)(Xb + ((size_t)u5 << 10) + lofs);
        uint2 w6 = *(const uint2*)(Xb + ((size_t)u6 << 10) + lofs);
        uint2 w7 = *(const uint2*)(Xb + ((size_t)u7 << 10) + lofs);
        edge1(w0); edge1(w1); edge1(w2); edge1(w3);
        edge1(w4); edge1(w5); edge1(w6); edge1(w7);
    }
    for (; i + 4 <= deg; i += 4) {
        int u0 = __builtin_amdgcn_readfirstlane(sl[i]);
        int u1 = __builtin_amdgcn_readfirstlane(sl[i + 1]);
        int u2 = __builtin_amdgcn_readfirstlane(sl[i + 2]);
        int u3 = __builtin_amdgcn_readfirstlane(sl[i + 3]);
        uint2 w0 = *(const uint2*)(Xb + ((size_t)u0 << 10) + lofs);
        uint2 w1 = *(const uint2*)(Xb + ((size_t)u1 << 10) + lofs);
        uint2 w2 = *(const uint2*)(Xb + ((size_t)u2 << 10) + lofs);
        uint2 w3 = *(const uint2*)(Xb + ((size_t)u3 << 10) + lofs);
        edge1(w0); edge1(w1); edge1(w2); edge1(w3);
    }
    for (; i < deg; ++i) {
        int u0 = __builtin_amdgcn_readfirstlane(sl[i]);
        uint2 w0 = *(const uint2*)(Xb + ((size_t)u0 << 10) + lofs);
        edge1(w0);
    }

    float inv = 1.f / s;
    float o0 = fmaxf(fmaf(oA.x, inv, bb.x), 0.f);
    float o1 = fmaxf(fmaf(oA.y, inv, bb.y), 0.f);
    float o2 = fmaxf(fmaf(oB.x, inv, bb.z), 0.f);
    float o3 = fmaxf(fmaf(oB.y, inv, bb.w), 0.f);
    ushort4 w4 = {f2bf(o0), f2bf(o1), f2bf(o2), f2bf(o3)};
    *(ushort4*)(H + ((size_t)wid << 8) + l * 4) = w4;
}

// ---------------- launcher ----------------

extern "C" void kernel_launch(void* const* d_in, const int* in_sizes, int n_in,
                              void* d_out, int out_size, void* d_ws, size_t ws_size,
                              hipStream_t stream) {
    MegaP P;
    P.x     = (const float*)d_in[0];
    P.ei    = (const int*)d_in[1];
    P.W1l   = (const float*)d_in[2];  P.b1l  = (const float*)d_in[3];
    P.W1r   = (const float*)d_in[4];  P.b1r  = (const float*)d_in[5];
    P.att1  = (const float*)d_in[6];  P.bias1 = (const float*)d_in[7];
    P.W2l   = (const float*)d_in[8];  P.b2l  = (const float*)d_in[9];
    P.W2r   = (const float*)d_in[10]; P.b2r  = (const float*)d_in[11];
    P.att2  = (const float*)d_in[12]; P.bias2 = (const float*)d_in[13];
    P.Wp1   = (const float*)d_in[14]; P.bp1  = (const float*)d_in[15];
    P.Wp2   = (const float*)d_in[16]; P.bp2  = (const float*)d_in[17];

    const int N = in_sizes[0] / 256;
    const int E = in_sizes[1] / 2;
    const int Mpad = ((N + 127) / 128) * 128;

    char* ws = (char*)d_ws;
    size_t o = 0;
    auto alloc = [&](size_t b) { char* p = ws + o; o = (o + b + 255) & ~(size_t)255; return p; };
    P.Abuf   = (u16*)alloc((size_t)Mpad * 256 * 2);
    P.XLR    = (u16*)alloc((size_t)Mpad * 512 * 2);
    P.WB1    = (u16*)alloc(512 * 256 * 2);
    P.WB2    = (u16*)alloc(512 * 256 * 2);
    P.Wpt    = (u16*)alloc(64 * 256 * 2);
    P.bc1    = (float*)alloc(512 * 4);
    P.bc2    = (float*)alloc(512 * 4);
    P.bpf    = (float*)alloc(64 * 4);
    P.cnt    = (int*)alloc((size_t)N * 4);
    P.slot   = (u16*)alloc((size_t)N * 64 * 2);
    P.outF   = (float*)d_out;
    P.N = N; P.E = E; P.Mpad = Mpad; P.Mt = Mpad / 128;

    hipMemsetAsync(P.cnt, 0, (size_t)N * 4, stream);
    if (Mpad > N)  // pad rows of Abuf read by g2/gp's gload_lds path
        hipMemsetAsync(P.Abuf + (size_t)N * 256, 0, (size_t)(Mpad - N) * 256 * 2, stream);

    // prep: weights + postW + bias + XCD-sharded scatter (256-thread, no LDS)
    const int nScat = ((E + 255) / 256) * 8;
    k_prep<<<1024 + 64 + 4 + nScat, 256, 0, stream>>>(P);

    const int ntile = P.Mt * 4;
    const int egrid = (N + 3) / 4;
    k_g1<<<ntile, 512, 0, stream>>>(P);
    k_edge<<<egrid, 256, 0, stream>>>(P.cnt, P.slot, P.XLR, P.att1, P.bias1, P.Abuf, N);
    k_g2<<<ntile, 512, 0, stream>>>(P);
    k_edge<<<egrid, 256, 0, stream>>>(P.cnt, P.slot, P.XLR, P.att2, P.bias2, P.Abuf, N);
    k_gp<<<P.Mt, 512, 0, stream>>>(P);
}